// Round 4
// baseline (19325.995 us; speedup 1.0000x reference)
//
#include <hip/hip_runtime.h>
#include <hip/hip_bf16.h>
#include <math.h>

// ---------------- problem dims ----------------
#define BATCH 32
#define S_TOK 197            // 14*14 + 1
#define HID 768
#define HEADS 12
#define DH 64
#define FF 3072
#define ROWS (BATCH * S_TOK) // 6304
#define PROWS (BATCH * 196)  // 6272

// All inputs fp32; output fp32 (reference dtypes). Intermediates fp32 in d_ws.

// ---------------- patchify: x(32,3,224,224) -> patches(6272,768) ----------------
// d = c*256 + i*16 + j  (channel-major flatten per patch)
__global__ __launch_bounds__(256) void patchify_kernel(
    const float* __restrict__ x, float* __restrict__ patches) {
  int r = blockIdx.x;            // 0..6271
  int b = r / 196, p = r % 196;
  int py = p / 14, px = p % 14;
  int tid = threadIdx.x;
#pragma unroll
  for (int kk = 0; kk < 3; ++kk) {
    int d = tid + 256 * kk;
    int c = d >> 8, rem = d & 255, i = rem >> 4, j = rem & 15;
    size_t src = (((size_t)(b * 3 + c) * 224) + py * 16 + i) * 224 + px * 16 + j;
    patches[(size_t)r * 768 + d] = x[src];
  }
}

// ---------------- assemble: out_res(row) = (cls | tokens) + posemb ----------------
__global__ __launch_bounds__(256) void assemble_kernel(
    const float* __restrict__ tokens, const float* __restrict__ cls,
    float* __restrict__ out_res) {
  int row = blockIdx.x;          // 0..6303
  int b = row / S_TOK, s = row % S_TOK;
  int tid = threadIdx.x;
#pragma unroll
  for (int kk = 0; kk < 3; ++kk) {
    int d = tid + 256 * kk;
    float t = (s == 0) ? cls[d]
                       : tokens[((size_t)(b * 196 + s - 1)) * 768 + d];
    float expo = (float)(d - (d & 1)) * (1.0f / 768.0f);
    float ang = (float)s * powf(10000.0f, -expo);
    t += (d & 1) ? cosf(ang) : sinf(ang);
    out_res[(size_t)row * 768 + d] = t;
  }
}

// ---------------- layernorm: dst = LN(src)*g + b ----------------
__global__ __launch_bounds__(256) void ln_kernel(
    const float* __restrict__ src, float* __restrict__ dst,
    const float* __restrict__ g, const float* __restrict__ bb) {
  int row = blockIdx.x;
  int tid = threadIdx.x;
  const float* xr = src + (size_t)row * 768;
  float v0 = xr[tid], v1 = xr[tid + 256], v2 = xr[tid + 512];
  float s = v0 + v1 + v2;
  float ss = fmaf(v0, v0, fmaf(v1, v1, v2 * v2));
#pragma unroll
  for (int off = 32; off; off >>= 1) {
    s += __shfl_xor(s, off);
    ss += __shfl_xor(ss, off);
  }
  __shared__ float rs[4], rss[4];
  int w = tid >> 6;
  if ((tid & 63) == 0) { rs[w] = s; rss[w] = ss; }
  __syncthreads();
  float S = rs[0] + rs[1] + rs[2] + rs[3];
  float SS = rss[0] + rss[1] + rss[2] + rss[3];
  float mean = S * (1.0f / 768.0f);
  float var = SS * (1.0f / 768.0f) - mean * mean;
  float inv = rsqrtf(var + 1e-5f);
  float* dr = dst + (size_t)row * 768;
  dr[tid]       = (v0 - mean) * inv * g[tid]       + bb[tid];
  dr[tid + 256] = (v1 - mean) * inv * g[tid + 256] + bb[tid + 256];
  dr[tid + 512] = (v2 - mean) * inv * g[tid + 512] + bb[tid + 512];
}

// ---------------- QKV: per (64-row tile, head): three 64x64x64 GEMMs ----------------
// q[b,s,h,e] = sum_d xs[b,s,h*64+d] * Wq[h,e,d] + bq[h,e]   (likewise k, v)
__global__ __launch_bounds__(256) void qkv_kernel(
    const float* __restrict__ xb,
    const float* __restrict__ Wq, const float* __restrict__ Wk,
    const float* __restrict__ Wv,
    const float* __restrict__ bq, const float* __restrict__ bk,
    const float* __restrict__ bv,
    float* __restrict__ q, float* __restrict__ k, float* __restrict__ v) {
  int m0 = blockIdx.x * 64;
  int h = blockIdx.y;
  __shared__ float Xs[64][65];   // +1 pad -> at worst 2-way aliasing (free)
  __shared__ float Wsh[64][65];  // reloaded per matrix (q, k, v)
  int tid = threadIdx.x;
  for (int idx = tid; idx < 64 * 64; idx += 256) {
    int r = idx >> 6, d = idx & 63;
    int row = m0 + r;
    Xs[r][d] = (row < ROWS) ? xb[(size_t)row * 768 + h * 64 + d] : 0.0f;
  }
  const float* Ws[3];
  Ws[0] = Wq + (size_t)h * 4096;
  Ws[1] = Wk + (size_t)h * 4096;
  Ws[2] = Wv + (size_t)h * 4096;
  int tx = tid & 15, ty = tid >> 4;
  float acc[3][4][4] = {};
#pragma unroll
  for (int w = 0; w < 3; ++w) {
    __syncthreads();  // covers Xs load (w=0) and prior Wsh reads (w>0)
    for (int idx = tid; idx < 4096; idx += 256)
      Wsh[idx >> 6][idx & 63] = Ws[w][idx];
    __syncthreads();
    for (int d = 0; d < 64; ++d) {
      float a[4], bw[4];
#pragma unroll
      for (int i = 0; i < 4; ++i) a[i] = Xs[ty * 4 + i][d];
#pragma unroll
      for (int j = 0; j < 4; ++j) bw[j] = Wsh[tx * 4 + j][d];
#pragma unroll
      for (int i = 0; i < 4; ++i)
#pragma unroll
        for (int j = 0; j < 4; ++j)
          acc[w][i][j] = fmaf(a[i], bw[j], acc[w][i][j]);
    }
  }
#pragma unroll
  for (int i = 0; i < 4; ++i) {
    int row = m0 + ty * 4 + i;
    if (row >= ROWS) continue;
    size_t base = (size_t)row * 768 + h * 64;
#pragma unroll
    for (int j = 0; j < 4; ++j) {
      int e = tx * 4 + j;
      q[base + e] = acc[0][i][j] + bq[h * 64 + e];
      k[base + e] = acc[1][i][j] + bk[h * 64 + e];
      v[base + e] = acc[2][i][j] + bv[h * 64 + e];
    }
  }
}

// ---------------- attention: per (b,h, 16-row chunk); K then V staged in LDS ----------------
// out_res[b,s,h,:] += softmax(q.kT/8) @ v
__global__ __launch_bounds__(256) void attn_kernel(
    const float* __restrict__ qg, const float* __restrict__ kg,
    const float* __restrict__ vg, float* __restrict__ out_res) {
  int b = blockIdx.x / HEADS, h = blockIdx.x % HEADS;
  int chunk = blockIdx.y;  // 0..12, rows chunk*16..+15
  __shared__ float KV[S_TOK * 64];   // XOR-swizzled: [t*64 + ((d+t)&63)]
  __shared__ float Ps[16 * S_TOK];
  __shared__ float Qs[4][64];
  int tid = threadIdx.x;
  int w = tid >> 6, l = tid & 63;
  size_t bh_base = (size_t)b * S_TOK * 768 + h * 64;
  for (int idx = tid; idx < S_TOK * 64; idx += 256) {
    int t = idx >> 6, d = idx & 63;
    KV[t * 64 + ((d + t) & 63)] = kg[bh_base + (size_t)t * 768 + d];
  }
  __syncthreads();
  for (int rr = 0; rr < 4; ++rr) {
    int lrow = w * 4 + rr;
    int s = chunk * 16 + lrow;
    bool act = (s < S_TOK);  // wave-uniform
    if (act) Qs[w][l] = qg[bh_base + (size_t)s * 768 + l];
    __syncthreads();
    float sc[4];
    float mx = -1e30f;
    if (act) {
#pragma unroll
      for (int m = 0; m < 4; ++m) {
        int t = l + 64 * m;
        if (t < S_TOK) {
          float acc = 0.0f;
#pragma unroll 8
          for (int d = 0; d < 64; ++d)
            acc = fmaf(Qs[w][d], KV[t * 64 + ((d + t) & 63)], acc);
          sc[m] = acc * 0.125f;
          mx = fmaxf(mx, sc[m]);
        } else sc[m] = -1e30f;
      }
    } else {
      sc[0] = sc[1] = sc[2] = sc[3] = -1e30f;
    }
#pragma unroll
    for (int off = 32; off; off >>= 1) mx = fmaxf(mx, __shfl_xor(mx, off));
    float ev[4];
    float sum = 0.0f;
#pragma unroll
    for (int m = 0; m < 4; ++m) {
      ev[m] = (sc[m] > -1e29f) ? expf(sc[m] - mx) : 0.0f;
      sum += ev[m];
    }
#pragma unroll
    for (int off = 32; off; off >>= 1) sum += __shfl_xor(sum, off);
    if (act) {
      float rinv = 1.0f / sum;
#pragma unroll
      for (int m = 0; m < 4; ++m) {
        int t = l + 64 * m;
        if (t < S_TOK) Ps[lrow * S_TOK + t] = ev[m] * rinv;
      }
    }
    __syncthreads();
  }
  for (int idx = tid; idx < S_TOK * 64; idx += 256) {
    int t = idx >> 6, d = idx & 63;
    KV[t * 64 + ((d + t) & 63)] = vg[bh_base + (size_t)t * 768 + d];
  }
  __syncthreads();
  for (int rr = 0; rr < 4; ++rr) {
    int lrow = w * 4 + rr;
    int s = chunk * 16 + lrow;
    if (s < S_TOK) {
      float acc = 0.0f;
      for (int t = 0; t < S_TOK; ++t)
        acc = fmaf(Ps[lrow * S_TOK + t], KV[t * 64 + ((l + t) & 63)], acc);
      out_res[bh_base + (size_t)s * 768 + l] += acc;
    }
  }
}

// ---------------- GEMM: C[M,N] (+)= A[M,K] * Bw[N,K]^T + bias, opt GELU ----------------
// 128x128 tile, BK=16, 256 threads, 8x8 per thread. All fp32.
template <int ACT, int ACC>
__global__ __launch_bounds__(256) void gemm_nt(
    const float* __restrict__ A, const float* __restrict__ Bw,
    const float* __restrict__ bias, float* __restrict__ C,
    int M, int N, int K) {
  __shared__ float As[16][128];
  __shared__ float Bs[16][128];
  int tid = threadIdx.x;
  int tx = tid & 15, ty = tid >> 4;
  int m0 = blockIdx.x * 128, n0 = blockIdx.y * 128;
  int lr = tid >> 1;            // 0..127
  int lk = (tid & 1) << 3;      // 0 or 8
  float acc[8][8] = {};
  for (int k0 = 0; k0 < K; k0 += 16) {
    float4 a0, a1;
    int arow = m0 + lr;
    if (arow < M) {
      const float* p = A + (size_t)arow * K + k0 + lk;
      a0 = *(const float4*)p;
      a1 = *(const float4*)(p + 4);
    } else {
      a0 = make_float4(0, 0, 0, 0);
      a1 = make_float4(0, 0, 0, 0);
    }
    const float* bp_ = Bw + (size_t)(n0 + lr) * K + k0 + lk;
    float4 b0 = *(const float4*)bp_;
    float4 b1 = *(const float4*)(bp_ + 4);
    __syncthreads();  // protect previous iter's LDS reads
    As[lk + 0][lr] = a0.x; As[lk + 1][lr] = a0.y;
    As[lk + 2][lr] = a0.z; As[lk + 3][lr] = a0.w;
    As[lk + 4][lr] = a1.x; As[lk + 5][lr] = a1.y;
    As[lk + 6][lr] = a1.z; As[lk + 7][lr] = a1.w;
    Bs[lk + 0][lr] = b0.x; Bs[lk + 1][lr] = b0.y;
    Bs[lk + 2][lr] = b0.z; Bs[lk + 3][lr] = b0.w;
    Bs[lk + 4][lr] = b1.x; Bs[lk + 5][lr] = b1.y;
    Bs[lk + 6][lr] = b1.z; Bs[lk + 7][lr] = b1.w;
    __syncthreads();
#pragma unroll
    for (int kk = 0; kk < 16; ++kk) {
      float a[8], bvv[8];
      *(float4*)&a[0]   = *(const float4*)&As[kk][ty * 8];
      *(float4*)&a[4]   = *(const float4*)&As[kk][ty * 8 + 4];
      *(float4*)&bvv[0] = *(const float4*)&Bs[kk][tx * 8];
      *(float4*)&bvv[4] = *(const float4*)&Bs[kk][tx * 8 + 4];
#pragma unroll
      for (int i = 0; i < 8; ++i)
#pragma unroll
        for (int j = 0; j < 8; ++j)
          acc[i][j] = fmaf(a[i], bvv[j], acc[i][j]);
    }
  }
  float bvals[8];
#pragma unroll
  for (int j = 0; j < 8; ++j) bvals[j] = bias[n0 + tx * 8 + j];
#pragma unroll
  for (int i = 0; i < 8; ++i) {
    int row = m0 + ty * 8 + i;
    if (row >= M) break;
    size_t cb = (size_t)row * N + n0 + tx * 8;
#pragma unroll
    for (int j = 0; j < 8; ++j) {
      float vv = acc[i][j] + bvals[j];
      if (ACT) vv = 0.5f * vv * (1.0f + erff(vv * 0.70710678118654752f));
      if (ACC) C[cb + j] += vv; else C[cb + j] = vv;
    }
  }
}

// ---------------- head: logits = cls_row @ Wo^T + bo; softmax -> fp32 out ----------------
__global__ __launch_bounds__(256) void head_kernel(
    const float* __restrict__ res, const float* __restrict__ Wo,
    const float* __restrict__ bo, float* __restrict__ out) {
  int b = blockIdx.x, tid = threadIdx.x;
  __shared__ float clsv[768];
  __shared__ float redm[4], reds[4];
  const float* r = res + (size_t)b * S_TOK * 768;
  clsv[tid] = r[tid];
  clsv[tid + 256] = r[tid + 256];
  clsv[tid + 512] = r[tid + 512];
  __syncthreads();
  float lg[4];
#pragma unroll
  for (int jj = 0; jj < 4; ++jj) {
    int o = tid + 256 * jj;
    float acc = -1e30f;
    if (o < 1000) {
      acc = bo[o];
      const float4* wr = (const float4*)(Wo + (size_t)o * 768);
      for (int d4 = 0; d4 < 192; ++d4) {
        float4 u = wr[d4];
        int d = d4 * 4;
        acc += clsv[d + 0] * u.x + clsv[d + 1] * u.y
             + clsv[d + 2] * u.z + clsv[d + 3] * u.w;
      }
    }
    lg[jj] = acc;
  }
  float mx = fmaxf(fmaxf(lg[0], lg[1]), fmaxf(lg[2], lg[3]));
#pragma unroll
  for (int off = 32; off; off >>= 1) mx = fmaxf(mx, __shfl_xor(mx, off));
  if ((tid & 63) == 0) redm[tid >> 6] = mx;
  __syncthreads();
  mx = fmaxf(fmaxf(redm[0], redm[1]), fmaxf(redm[2], redm[3]));
  float ev[4];
  float sum = 0.0f;
#pragma unroll
  for (int jj = 0; jj < 4; ++jj) {
    int o = tid + 256 * jj;
    ev[jj] = (o < 1000) ? expf(lg[jj] - mx) : 0.0f;
    sum += ev[jj];
  }
#pragma unroll
  for (int off = 32; off; off >>= 1) sum += __shfl_xor(sum, off);
  if ((tid & 63) == 0) reds[tid >> 6] = sum;
  __syncthreads();
  sum = reds[0] + reds[1] + reds[2] + reds[3];
  float rinv = 1.0f / sum;
#pragma unroll
  for (int jj = 0; jj < 4; ++jj) {
    int o = tid + 256 * jj;
    if (o < 1000) out[(size_t)b * 1000 + o] = ev[jj] * rinv;
  }
}

// ---------------- launch ----------------
extern "C" void kernel_launch(void* const* d_in, const int* in_sizes, int n_in,
                              void* d_out, int out_size, void* d_ws, size_t ws_size,
                              hipStream_t stream) {
  (void)in_sizes; (void)n_in; (void)out_size; (void)ws_size;
  const float* x   = (const float*)d_in[0];
  const float* Wp  = (const float*)d_in[1];
  const float* bp  = (const float*)d_in[2];
  const float* cls = (const float*)d_in[3];
  const float* Wq  = (const float*)d_in[4];
  const float* bq  = (const float*)d_in[5];
  const float* Wk  = (const float*)d_in[6];
  const float* bk  = (const float*)d_in[7];
  const float* Wv  = (const float*)d_in[8];
  const float* bv  = (const float*)d_in[9];
  const float* g1  = (const float*)d_in[10];
  const float* b1n = (const float*)d_in[11];
  const float* g2  = (const float*)d_in[12];
  const float* b2n = (const float*)d_in[13];
  const float* W1  = (const float*)d_in[14];
  const float* bm1 = (const float*)d_in[15];
  const float* W2  = (const float*)d_in[16];
  const float* bm2 = (const float*)d_in[17];
  const float* Wo  = (const float*)d_in[18];
  const float* bo  = (const float*)d_in[19];

  float* ws = (float*)d_ws;
  const size_t RH = (size_t)ROWS * HID;  // 4,841,472 floats
  float* out_res = ws;            // residual stream (B,S,HID)
  float* xb      = ws + RH;       // LN output / token buffer
  float* qb      = ws + 2 * RH;
  float* kb      = ws + 3 * RH;
  float* vb      = ws + 4 * RH;
  float* h1      = ws + 2 * RH;   // MLP hidden (ROWS x 3072) = 4*RH, aliases q/k/v (sequenced)
  float* patches = ws + 2 * RH;   // (6272 x 768), aliases h1 (sequenced)
  // total ws use: 6*RH floats = 116,195,328 bytes

  patchify_kernel<<<PROWS, 256, 0, stream>>>(x, patches);
  gemm_nt<0, 0><<<dim3(49, 6), 256, 0, stream>>>(patches, Wp, bp, xb,
                                                 PROWS, 768, 768);
  assemble_kernel<<<ROWS, 256, 0, stream>>>(xb, cls, out_res);

  for (int blk = 0; blk < 12; ++blk) {
    ln_kernel<<<ROWS, 256, 0, stream>>>(out_res, xb, g1 + blk * 768, b1n + blk * 768);
    qkv_kernel<<<dim3(99, 12), 256, 0, stream>>>(
        xb, Wq + (size_t)blk * 49152, Wk + (size_t)blk * 49152, Wv + (size_t)blk * 49152,
        bq + blk * 768, bk + blk * 768, bv + blk * 768, qb, kb, vb);
    attn_kernel<<<dim3(BATCH * HEADS, 13), 256, 0, stream>>>(qb, kb, vb, out_res);
    ln_kernel<<<ROWS, 256, 0, stream>>>(out_res, xb, g2 + blk * 768, b2n + blk * 768);
    gemm_nt<1, 0><<<dim3(50, 24), 256, 0, stream>>>(
        xb, W1 + (size_t)blk * 2359296, bm1 + blk * 3072, h1, ROWS, FF, 768);
    gemm_nt<0, 1><<<dim3(50, 6), 256, 0, stream>>>(
        h1, W2 + (size_t)blk * 2359296, bm2 + blk * 768, out_res, ROWS, 768, FF);
  }
  head_kernel<<<BATCH, 256, 0, stream>>>(out_res, Wo, bo, (float*)d_out);
}

// Round 5
// 6563.847 us; speedup vs baseline: 2.9443x; 2.9443x over previous
//
#include <hip/hip_runtime.h>
#include <hip/hip_bf16.h>
#include <math.h>

// ---------------- problem dims ----------------
#define BATCH 32
#define S_TOK 197
#define HID 768
#define HEADS 12
#define DH 64
#define FF 3072
#define ROWS (BATCH * S_TOK) // 6304
#define PROWS (BATCH * 196)  // 6272

typedef __attribute__((ext_vector_type(8))) short bf16x8;
typedef __attribute__((ext_vector_type(4))) float f32x4;
#define MFMA16(a, b, c) __builtin_amdgcn_mfma_f32_16x16x32_bf16(a, b, c, 0, 0, 0)
typedef const __attribute__((address_space(1))) void* gas_t;
typedef __attribute__((address_space(3))) void* las_t;

__device__ __forceinline__ float bfu(unsigned short h) {
  return __uint_as_float(((unsigned)h) << 16);
}
__device__ __forceinline__ unsigned short f2bf(float f) {
  union { float f; unsigned u; } v; v.f = f;
  unsigned r = v.u + 0x7fffu + ((v.u >> 16) & 1u);
  return (unsigned short)(r >> 16);
}

// ---------------- patchify: x(32,3,224,224) -> patches(6272,768) fp32 ----------------
__global__ __launch_bounds__(256) void patchify_kernel(
    const float* __restrict__ x, float* __restrict__ patches) {
  int r = blockIdx.x;
  int b = r / 196, p = r % 196;
  int py = p / 14, px = p % 14;
  int tid = threadIdx.x;
#pragma unroll
  for (int kk = 0; kk < 3; ++kk) {
    int d = tid + 256 * kk;
    int c = d >> 8, rem = d & 255, i = rem >> 4, j = rem & 15;
    size_t src = (((size_t)(b * 3 + c) * 224) + py * 16 + i) * 224 + px * 16 + j;
    patches[(size_t)r * 768 + d] = x[src];
  }
}

// ---------------- hi/lo bf16 split converter ----------------
__global__ __launch_bounds__(256) void convert_hl_kernel(
    const float* __restrict__ src, unsigned short* __restrict__ h,
    unsigned short* __restrict__ l, int n) {
  int i = (blockIdx.x * 256 + threadIdx.x) * 4;
  int stride = gridDim.x * 1024;
  for (; i < n; i += stride) {
    float4 v = *(const float4*)(src + i);
    ushort4 hh, ll;
    hh.x = f2bf(v.x); ll.x = f2bf(v.x - bfu(hh.x));
    hh.y = f2bf(v.y); ll.y = f2bf(v.y - bfu(hh.y));
    hh.z = f2bf(v.z); ll.z = f2bf(v.z - bfu(hh.z));
    hh.w = f2bf(v.w); ll.w = f2bf(v.w - bfu(hh.w));
    *(ushort4*)(h + i) = hh;
    *(ushort4*)(l + i) = ll;
  }
}

// ---------------- assemble: out_res(row) = (cls | tokens) + posemb ----------------
__global__ __launch_bounds__(256) void assemble_kernel(
    const float* __restrict__ tokens, const float* __restrict__ cls,
    float* __restrict__ out_res) {
  int row = blockIdx.x;
  int b = row / S_TOK, s = row % S_TOK;
  int tid = threadIdx.x;
#pragma unroll
  for (int kk = 0; kk < 3; ++kk) {
    int d = tid + 256 * kk;
    float t = (s == 0) ? cls[d]
                       : tokens[((size_t)(b * 196 + s - 1)) * 768 + d];
    float expo = (float)(d - (d & 1)) * (1.0f / 768.0f);
    float ang = (float)s * powf(10000.0f, -expo);
    t += (d & 1) ? cosf(ang) : sinf(ang);
    out_res[(size_t)row * 768 + d] = t;
  }
}

// ---------------- layernorm -> bf16 hi/lo ----------------
__global__ __launch_bounds__(256) void ln_kernel(
    const float* __restrict__ src, unsigned short* __restrict__ dh,
    unsigned short* __restrict__ dl,
    const float* __restrict__ g, const float* __restrict__ bb) {
  int row = blockIdx.x;
  int tid = threadIdx.x;
  const float* xr = src + (size_t)row * 768;
  float v0 = xr[tid], v1 = xr[tid + 256], v2 = xr[tid + 512];
  float s = v0 + v1 + v2;
  float ss = fmaf(v0, v0, fmaf(v1, v1, v2 * v2));
#pragma unroll
  for (int off = 32; off; off >>= 1) {
    s += __shfl_xor(s, off);
    ss += __shfl_xor(ss, off);
  }
  __shared__ float rs[4], rss[4];
  int w = tid >> 6;
  if ((tid & 63) == 0) { rs[w] = s; rss[w] = ss; }
  __syncthreads();
  float S = rs[0] + rs[1] + rs[2] + rs[3];
  float SS = rss[0] + rss[1] + rss[2] + rss[3];
  float mean = S * (1.0f / 768.0f);
  float var = SS * (1.0f / 768.0f) - mean * mean;
  float inv = rsqrtf(var + 1e-5f);
  size_t base = (size_t)row * 768;
#pragma unroll
  for (int kk = 0; kk < 3; ++kk) {
    int d = tid + 256 * kk;
    float vv = (kk == 0) ? v0 : (kk == 1 ? v1 : v2);
    float y = (vv - mean) * inv * g[d] + bb[d];
    unsigned short hh = f2bf(y);
    dh[base + d] = hh;
    dl[base + d] = f2bf(y - bfu(hh));
  }
}

// ---------------- QKV (VALU, fp32): per (64-row tile, head) ----------------
__global__ __launch_bounds__(256) void qkv_kernel(
    const unsigned short* __restrict__ xh, const unsigned short* __restrict__ xl,
    const float* __restrict__ Wq, const float* __restrict__ Wk,
    const float* __restrict__ Wv,
    const float* __restrict__ bq, const float* __restrict__ bk,
    const float* __restrict__ bv,
    float* __restrict__ q, float* __restrict__ k, float* __restrict__ v) {
  int m0 = blockIdx.x * 64;
  int h = blockIdx.y;
  __shared__ float Xs[64][65];
  __shared__ float Wsh[64][65];
  int tid = threadIdx.x;
  for (int idx = tid; idx < 64 * 64; idx += 256) {
    int r = idx >> 6, d = idx & 63;
    int row = m0 + r;
    size_t off = (size_t)row * 768 + h * 64 + d;
    Xs[r][d] = (row < ROWS) ? (bfu(xh[off]) + bfu(xl[off])) : 0.0f;
  }
  const float* Ws[3];
  Ws[0] = Wq + (size_t)h * 4096;
  Ws[1] = Wk + (size_t)h * 4096;
  Ws[2] = Wv + (size_t)h * 4096;
  int tx = tid & 15, ty = tid >> 4;
  float acc[3][4][4] = {};
#pragma unroll
  for (int w = 0; w < 3; ++w) {
    __syncthreads();
    for (int idx = tid; idx < 4096; idx += 256)
      Wsh[idx >> 6][idx & 63] = Ws[w][idx];
    __syncthreads();
    for (int d = 0; d < 64; ++d) {
      float a[4], bw[4];
#pragma unroll
      for (int i = 0; i < 4; ++i) a[i] = Xs[ty * 4 + i][d];
#pragma unroll
      for (int j = 0; j < 4; ++j) bw[j] = Wsh[tx * 4 + j][d];
#pragma unroll
      for (int i = 0; i < 4; ++i)
#pragma unroll
        for (int j = 0; j < 4; ++j)
          acc[w][i][j] = fmaf(a[i], bw[j], acc[w][i][j]);
    }
  }
#pragma unroll
  for (int i = 0; i < 4; ++i) {
    int row = m0 + ty * 4 + i;
    if (row >= ROWS) continue;
    size_t base = (size_t)row * 768 + h * 64;
#pragma unroll
    for (int j = 0; j < 4; ++j) {
      int e = tx * 4 + j;
      q[base + e] = acc[0][i][j] + bq[h * 64 + e];
      k[base + e] = acc[1][i][j] + bk[h * 64 + e];
      v[base + e] = acc[2][i][j] + bv[h * 64 + e];
    }
  }
}

// ---------------- MFMA attention: block = (b, h, 16-row q-tile) ----------------
// K staged bf16 [208][72]; Vt staged transposed bf16 [64][232]; P bf16 [16][232].
#define KS 72
#define VS 232
__global__ __launch_bounds__(256) void attn_kernel(
    const float* __restrict__ qg, const float* __restrict__ kg,
    const float* __restrict__ vg, float* __restrict__ out_res) {
  __shared__ __attribute__((aligned(16))) unsigned short KVu[208 * KS]; // 29952B; reused as Vt[64][VS]
  __shared__ __attribute__((aligned(16))) unsigned short Qu[16 * KS];
  __shared__ __attribute__((aligned(16))) unsigned short Pu[16 * VS];
  __shared__ float red_m[4][16], red_l[4][16];
  int b = blockIdx.x / HEADS, h = blockIdx.x % HEADS;
  int chunk = blockIdx.y;
  int tid = threadIdx.x;
  int w = tid >> 6, lane = tid & 63;
  int fm = lane & 15, quad = lane >> 4;
  size_t bh = (size_t)b * S_TOK * 768 + h * 64;

  // stage K (bf16) and Q (rows clamped), zero Pu tail cols [208,224)
  for (int idx = tid; idx < S_TOK * 64; idx += 256) {
    int t = idx >> 6, d = idx & 63;
    KVu[t * KS + d] = f2bf(kg[bh + (size_t)t * 768 + d]);
  }
  for (int idx = tid; idx < 16 * 64; idx += 256) {
    int r = idx >> 6, d = idx & 63;
    int s = chunk * 16 + r; if (s > 196) s = 196;
    Qu[r * KS + d] = f2bf(qg[bh + (size_t)s * 768 + d]);
  }
  { int r = tid >> 4, c = 208 + (tid & 15); Pu[r * VS + c] = 0; }
  __syncthreads();

  // phase 1: S = Q K^T * 0.125 ; wave w handles t-tiles {w, w+4, w+8, w+12}
  bf16x8 qa0 = *(const bf16x8*)&Qu[fm * KS + quad * 8];
  bf16x8 qa1 = *(const bf16x8*)&Qu[fm * KS + 32 + quad * 8];
  float sreg[4][4];
  f32x4 zero4 = {0.0f, 0.0f, 0.0f, 0.0f};
#pragma unroll
  for (int i = 0; i < 4; ++i) {
    int tt = w + 4 * i;
    if (tt < 13) {
      f32x4 sc = zero4;
      bf16x8 kb0 = *(const bf16x8*)&KVu[(tt * 16 + fm) * KS + quad * 8];
      bf16x8 kb1 = *(const bf16x8*)&KVu[(tt * 16 + fm) * KS + 32 + quad * 8];
      sc = MFMA16(qa0, kb0, sc);
      sc = MFMA16(qa1, kb1, sc);
      bool bad = (tt == 12) && (fm >= 5);
#pragma unroll
      for (int r = 0; r < 4; ++r) sreg[i][r] = bad ? -1e30f : sc[r] * 0.125f;
    } else {
#pragma unroll
      for (int r = 0; r < 4; ++r) sreg[i][r] = -1e30f;
    }
  }
  __syncthreads();  // everyone done reading KVu (K) and Qu

  // stage V transposed (overwrites KVu), zero its tail cols [197,224)
  for (int idx = tid; idx < S_TOK * 64; idx += 256) {
    int t = idx >> 6, d = idx & 63;
    KVu[d * VS + t] = f2bf(vg[bh + (size_t)t * 768 + d]);
  }
  for (int idx = tid; idx < 64 * 27; idx += 256) {
    int d = idx / 27, c = 197 + idx % 27;
    KVu[d * VS + c] = 0;
  }
  // row-max reduction (registers + shuffles; LDS red_m independent of KVu)
  float mx[4];
#pragma unroll
  for (int r = 0; r < 4; ++r) {
    float m_ = sreg[0][r];
#pragma unroll
    for (int i = 1; i < 4; ++i) m_ = fmaxf(m_, sreg[i][r]);
    mx[r] = m_;
  }
#pragma unroll
  for (int off = 1; off < 16; off <<= 1)
#pragma unroll
    for (int r = 0; r < 4; ++r) mx[r] = fmaxf(mx[r], __shfl_xor(mx[r], off));
  if (fm == 0) {
#pragma unroll
    for (int r = 0; r < 4; ++r) red_m[w][quad * 4 + r] = mx[r];
  }
  __syncthreads();  // red_m ready AND Vt staged
  float mxf[4], ls[4];
#pragma unroll
  for (int r = 0; r < 4; ++r) {
    int rr = quad * 4 + r;
    mxf[r] = fmaxf(fmaxf(red_m[0][rr], red_m[1][rr]),
                   fmaxf(red_m[2][rr], red_m[3][rr]));
    ls[r] = 0.0f;
  }
#pragma unroll
  for (int i = 0; i < 4; ++i)
#pragma unroll
    for (int r = 0; r < 4; ++r) {
      float e = (sreg[i][r] > -1e29f) ? expf(sreg[i][r] - mxf[r]) : 0.0f;
      sreg[i][r] = e;
      ls[r] += e;
    }
#pragma unroll
  for (int off = 1; off < 16; off <<= 1)
#pragma unroll
    for (int r = 0; r < 4; ++r) ls[r] += __shfl_xor(ls[r], off);
  if (fm == 0) {
#pragma unroll
    for (int r = 0; r < 4; ++r) red_l[w][quad * 4 + r] = ls[r];
  }
  __syncthreads();
  float rinv[4];
#pragma unroll
  for (int r = 0; r < 4; ++r) {
    int rr = quad * 4 + r;
    rinv[r] = 1.0f / (red_l[0][rr] + red_l[1][rr] + red_l[2][rr] + red_l[3][rr]);
  }
  // write P (bf16) in [row][t] layout
#pragma unroll
  for (int i = 0; i < 4; ++i) {
    int tt = w + 4 * i;
    if (tt < 13) {
#pragma unroll
      for (int r = 0; r < 4; ++r)
        Pu[(quad * 4 + r) * VS + tt * 16 + fm] = f2bf(sreg[i][r] * rinv[r]);
    }
  }
  __syncthreads();

  // phase 2: O = P @ V ; wave w owns d-tile w (cols w*16..w*16+15)
  f32x4 oc = zero4;
#pragma unroll
  for (int kt = 0; kt < 7; ++kt) {
    bf16x8 pa = *(const bf16x8*)&Pu[fm * VS + kt * 32 + quad * 8];
    bf16x8 vb = *(const bf16x8*)&KVu[(w * 16 + fm) * VS + kt * 32 + quad * 8];
    oc = MFMA16(pa, vb, oc);
  }
#pragma unroll
  for (int r = 0; r < 4; ++r) {
    int srow = chunk * 16 + quad * 4 + r;
    if (srow < S_TOK) {
      size_t addr = ((size_t)(b * S_TOK + srow)) * 768 + h * 64 + w * 16 + fm;
      out_res[addr] += oc[r];
    }
  }
}

// ---------------- MFMA GEMM, hi/lo split: C = A*B^T (+bias)(+GELU) ----------------
// A[M][K] bf16 hi/lo, B[N][K] bf16 hi/lo. 128x128 tile, BK=32, 4 waves (2x2 of 64x64).
// OMODE: 0 = fp32 store, 1 = fp32 accumulate, 2 = bf16 hi/lo store
template <int ACT, int OMODE>
__global__ __launch_bounds__(256) void gemm_hl(
    const unsigned short* __restrict__ Ah, const unsigned short* __restrict__ Al,
    int lda,
    const unsigned short* __restrict__ Bh, const unsigned short* __restrict__ Bl,
    int ldb,
    const float* __restrict__ bias, float* __restrict__ C,
    unsigned short* __restrict__ Ch, unsigned short* __restrict__ Cl,
    int ldc, int M, int K) {
  __shared__ __attribute__((aligned(16))) unsigned short sm[4 * 4096]; // Ah|Al|Bh|Bl [128][32]
  int tid = threadIdx.x;
  int w = tid >> 6, lane = tid & 63;
  int m0 = blockIdx.x * 128, n0 = blockIdx.y * 128;
  const unsigned short* src = (w == 0) ? Ah : (w == 1) ? Al : (w == 2) ? Bh : Bl;
  int srow0 = (w < 2) ? m0 : n0;
  int sld = (w < 2) ? lda : ldb;
  unsigned short* sbase = sm + w * 4096;
  int fm = lane & 15, quad = lane >> 4;
  int wm = w & 1, wn = w >> 1;
  f32x4 zero4 = {0.0f, 0.0f, 0.0f, 0.0f};
  f32x4 acc[4][4];
#pragma unroll
  for (int i = 0; i < 4; ++i)
#pragma unroll
    for (int j = 0; j < 4; ++j) acc[i][j] = zero4;

  int srow_l = lane >> 2, scol = (lane & 3) * 8;
  for (int k0 = 0; k0 < K; k0 += 32) {
    __syncthreads();  // prior iter's LDS reads done
#pragma unroll
    for (int c = 0; c < 8; ++c) {
      const unsigned short* g =
          src + (size_t)(srow0 + c * 16 + srow_l) * sld + k0 + scol;
      __builtin_amdgcn_global_load_lds((gas_t)g, (las_t)(sbase + c * 512), 16, 0, 0);
    }
    __syncthreads();  // DMA drained (vmcnt before barrier)
    bf16x8 a_h[4], a_l[4];
#pragma unroll
    for (int i = 0; i < 4; ++i) {
      int row = wm * 64 + i * 16 + fm;
      a_h[i] = *(const bf16x8*)&sm[row * 32 + quad * 8];
      a_l[i] = *(const bf16x8*)&sm[4096 + row * 32 + quad * 8];
    }
#pragma unroll
    for (int j = 0; j < 4; ++j) {
      int rowb = wn * 64 + j * 16 + fm;
      bf16x8 b_h = *(const bf16x8*)&sm[8192 + rowb * 32 + quad * 8];
      bf16x8 b_l = *(const bf16x8*)&sm[12288 + rowb * 32 + quad * 8];
#pragma unroll
      for (int i = 0; i < 4; ++i) {
        acc[i][j] = MFMA16(a_h[i], b_h, acc[i][j]);
        acc[i][j] = MFMA16(a_l[i], b_h, acc[i][j]);
        acc[i][j] = MFMA16(a_h[i], b_l, acc[i][j]);
      }
    }
  }
  // epilogue
#pragma unroll
  for (int j = 0; j < 4; ++j) {
    int col = n0 + wn * 64 + j * 16 + fm;
    float bj = bias ? bias[col] : 0.0f;
#pragma unroll
    for (int i = 0; i < 4; ++i) {
#pragma unroll
      for (int r = 0; r < 4; ++r) {
        int row = m0 + wm * 64 + i * 16 + quad * 4 + r;
        if (row < M) {
          float vv = acc[i][j][r] + bj;
          if (ACT) vv = 0.5f * vv * (1.0f + erff(vv * 0.70710678118654752f));
          size_t cb = (size_t)row * ldc + col;
          if (OMODE == 0) {
            C[cb] = vv;
          } else if (OMODE == 1) {
            C[cb] += vv;
          } else {
            unsigned short hh = f2bf(vv);
            Ch[cb] = hh;
            Cl[cb] = f2bf(vv - bfu(hh));
          }
        }
      }
    }
  }
}

// ---------------- head: logits = cls_row @ Wo^T + bo; softmax -> fp32 out ----------------
__global__ __launch_bounds__(256) void head_kernel(
    const float* __restrict__ res, const float* __restrict__ Wo,
    const float* __restrict__ bo, float* __restrict__ out) {
  int b = blockIdx.x, tid = threadIdx.x;
  __shared__ float clsv[768];
  __shared__ float redm[4], reds[4];
  const float* r = res + (size_t)b * S_TOK * 768;
  clsv[tid] = r[tid];
  clsv[tid + 256] = r[tid + 256];
  clsv[tid + 512] = r[tid + 512];
  __syncthreads();
  float lg[4];
#pragma unroll
  for (int jj = 0; jj < 4; ++jj) {
    int o = tid + 256 * jj;
    float acc = -1e30f;
    if (o < 1000) {
      acc = bo[o];
      const float4* wr = (const float4*)(Wo + (size_t)o * 768);
      for (int d4 = 0; d4 < 192; ++d4) {
        float4 u = wr[d4];
        int d = d4 * 4;
        acc += clsv[d + 0] * u.x + clsv[d + 1] * u.y
             + clsv[d + 2] * u.z + clsv[d + 3] * u.w;
      }
    }
    lg[jj] = acc;
  }
  float mx = fmaxf(fmaxf(lg[0], lg[1]), fmaxf(lg[2], lg[3]));
#pragma unroll
  for (int off = 32; off; off >>= 1) mx = fmaxf(mx, __shfl_xor(mx, off));
  if ((tid & 63) == 0) redm[tid >> 6] = mx;
  __syncthreads();
  mx = fmaxf(fmaxf(redm[0], redm[1]), fmaxf(redm[2], redm[3]));
  float ev[4];
  float sum = 0.0f;
#pragma unroll
  for (int jj = 0; jj < 4; ++jj) {
    int o = tid + 256 * jj;
    ev[jj] = (o < 1000) ? expf(lg[jj] - mx) : 0.0f;
    sum += ev[jj];
  }
#pragma unroll
  for (int off = 32; off; off >>= 1) sum += __shfl_xor(sum, off);
  if ((tid & 63) == 0) reds[tid >> 6] = sum;
  __syncthreads();
  sum = reds[0] + reds[1] + reds[2] + reds[3];
  float rinv = 1.0f / sum;
#pragma unroll
  for (int jj = 0; jj < 4; ++jj) {
    int o = tid + 256 * jj;
    if (o < 1000) out[(size_t)b * 1000 + o] = ev[jj] * rinv;
  }
}

// ---------------- launch ----------------
extern "C" void kernel_launch(void* const* d_in, const int* in_sizes, int n_in,
                              void* d_out, int out_size, void* d_ws, size_t ws_size,
                              hipStream_t stream) {
  (void)in_sizes; (void)n_in; (void)out_size; (void)ws_size;
  const float* x   = (const float*)d_in[0];
  const float* Wp  = (const float*)d_in[1];
  const float* bp  = (const float*)d_in[2];
  const float* cls = (const float*)d_in[3];
  const float* Wq  = (const float*)d_in[4];
  const float* bq  = (const float*)d_in[5];
  const float* Wk  = (const float*)d_in[6];
  const float* bk  = (const float*)d_in[7];
  const float* Wv  = (const float*)d_in[8];
  const float* bv  = (const float*)d_in[9];
  const float* g1  = (const float*)d_in[10];
  const float* b1n = (const float*)d_in[11];
  const float* g2  = (const float*)d_in[12];
  const float* b2n = (const float*)d_in[13];
  const float* W1  = (const float*)d_in[14];
  const float* bm1 = (const float*)d_in[15];
  const float* W2  = (const float*)d_in[16];
  const float* bm2 = (const float*)d_in[17];
  const float* Wo  = (const float*)d_in[18];
  const float* bo  = (const float*)d_in[19];

  float* ws = (float*)d_ws;
  const size_t RH = (size_t)ROWS * HID;  // 4,841,472 floats per slot
  float* out_res = ws;                     // slot 0: residual fp32
  unsigned short* xbh = (unsigned short*)(ws + RH);        // slot 1: LN out hi/lo
  unsigned short* xbl = xbh + RH;
  float* qb = ws + 2 * RH;                 // slot 2
  float* kb = ws + 3 * RH;                 // slot 3
  float* vb = ws + 4 * RH;                 // slot 4
  unsigned short* Wc = (unsigned short*)(ws + 5 * RH);     // slot 5: weight scratch
  // aliases (sequenced): patches fp32 in slot2; patch hi/lo in slot3;
  // tokens fp32 in slot4; h1 hi -> slot2, h1 lo -> slot3 (6304x1536 bf16 each)
  float* patches = qb;
  unsigned short* ph = (unsigned short*)kb;
  unsigned short* pl = ph + (size_t)PROWS * 768;
  float* tokens = vb;
  unsigned short* h1h = (unsigned short*)qb;
  unsigned short* h1l = (unsigned short*)kb;

  const size_t WQKV = (size_t)HEADS * DH * DH;  // 49152
  const size_t WMLP = (size_t)FF * HID;         // 2359296
  unsigned short* w1h = Wc;
  unsigned short* w1l = Wc + WMLP;
  unsigned short* w2h = Wc + 2 * WMLP;
  unsigned short* w2l = Wc + 3 * WMLP;

  // ---- patch embedding ----
  patchify_kernel<<<PROWS, 256, 0, stream>>>(x, patches);
  convert_hl_kernel<<<1024, 256, 0, stream>>>(patches, ph, pl, PROWS * 768);
  convert_hl_kernel<<<512, 256, 0, stream>>>(Wp, w1h, w1l, 768 * 768);
  gemm_hl<0, 0><<<dim3(49, 6), 256, 0, stream>>>(
      ph, pl, 768, w1h, w1l, 768, bp, tokens, nullptr, nullptr, 768, PROWS, 768);
  assemble_kernel<<<ROWS, 256, 0, stream>>>(tokens, cls, out_res);

  for (int blk = 0; blk < 12; ++blk) {
    ln_kernel<<<ROWS, 256, 0, stream>>>(out_res, xbh, xbl,
                                        g1 + blk * 768, b1n + blk * 768);
    qkv_kernel<<<dim3(99, 12), 256, 0, stream>>>(
        xbh, xbl, Wq + blk * WQKV, Wk + blk * WQKV, Wv + blk * WQKV,
        bq + blk * 768, bk + blk * 768, bv + blk * 768, qb, kb, vb);
    attn_kernel<<<dim3(BATCH * HEADS, 13), 256, 0, stream>>>(qb, kb, vb, out_res);
    ln_kernel<<<ROWS, 256, 0, stream>>>(out_res, xbh, xbl,
                                        g2 + blk * 768, b2n + blk * 768);
    convert_hl_kernel<<<1024, 256, 0, stream>>>(W1 + blk * WMLP, w1h, w1l, (int)WMLP);
    convert_hl_kernel<<<1024, 256, 0, stream>>>(W2 + blk * WMLP, w2h, w2l, (int)WMLP);
    for (int c = 0; c < 2; ++c) {
      // h1[:, c-half] = GELU(x @ W1_chunk^T + bm1_chunk)   (N = 1536, K = 768)
      gemm_hl<1, 2><<<dim3(50, 12), 256, 0, stream>>>(
          xbh, xbl, 768,
          w1h + (size_t)c * 1536 * 768, w1l + (size_t)c * 1536 * 768, 768,
          bm1 + blk * FF + c * 1536, nullptr, h1h, h1l, 1536, ROWS, 768);
      // out_res += h1_chunk @ W2_chunk^T (+ bm2 on first chunk)  (N=768, K=1536)
      gemm_hl<0, 1><<<dim3(50, 6), 256, 0, stream>>>(
          h1h, h1l, 1536,
          w2h + (size_t)c * 1536, w2l + (size_t)c * 1536, FF,
          (c == 0) ? (bm2 + blk * 768) : nullptr, out_res, nullptr, nullptr,
          768, ROWS, 1536);
    }
  }
  head_kernel<<<BATCH, 256, 0, stream>>>(out_res, Wo, bo, (float*)d_out);
}